// Round 1
// baseline (667.345 us; speedup 1.0000x reference)
//
#include <hip/hip_runtime.h>

// ILCBaseNode: T=32 steps of IF-neuron + grouped-conv feedback.
// One wave (64 lanes) per (batch, group) chain; lane o = output neuron o.
// 32768 chains = 8192 blocks x 4 waves.
//
// R1: replace 64x v_readlane spike broadcast with LDS-staged spike vector
//     (1 ds_write + 16 broadcast ds_read_b128 per step); pin weight rows in
//     VGPRs via empty asm (compiler had demoted them -> VGPR_Count=40 and
//     per-step weight refetch); 2-deep x prefetch; non-temporal spike stores.

#define T_STEPS 32
#define BATCH 512
#define OUTD 4096           // 64 groups * 64 neurons
#define STEP_STRIDE ((size_t)BATCH * OUTD)

__global__ __launch_bounds__(256, 4)
void ilc_snn_kernel(const float* __restrict__ x_seq,
                    const float* __restrict__ conn_w,
                    const float* __restrict__ conn_b,
                    float* __restrict__ out)
{
    const int lane  = threadIdx.x & 63;
    const int wid   = threadIdx.x >> 6;
    const int chain = blockIdx.x * 4 + wid;   // 0..32767
    const int b     = chain >> 6;             // 0..511
    const int a     = chain & 63;             // 0..63

    // Per-wave spike staging buffer (wave-private slice; no block barrier
    // needed -- wave-lockstep write->read with lgkmcnt ordering).
    __shared__ float4 sp4_lds[4][16];
    float* sp_row = (float*)&sp4_lds[wid][0];
    const float4* sp4 = &sp4_lds[wid][0];

    // Lane o holds weight row w[a][o][0..63] in registers (64 VGPRs).
    // The asm pins each loaded value: its origin becomes opaque so the
    // compiler cannot rematerialize the global loads inside the t-loop.
    float w[64];
    const float4* wq = (const float4*)(conn_w + ((size_t)(a * 64 + lane)) * 64);
#pragma unroll
    for (int k = 0; k < 16; ++k) {
        float4 q = wq[k];
        asm volatile("" : "+v"(q.x), "+v"(q.y), "+v"(q.z), "+v"(q.w));
        w[4 * k + 0] = q.x;
        w[4 * k + 1] = q.y;
        w[4 * k + 2] = q.z;
        w[4 * k + 3] = q.w;
    }
    const float bias = conn_b[a * 64 + lane];

    const size_t base = (size_t)b * OUTD + (size_t)(a * 64 + lane);
    const float* xp = x_seq + base;
    float* op = out + base;

    float v = 0.0f, fb = 0.0f;
    // 2-deep prefetch of the input stream.
    float x0 = xp[0];
    float x1 = xp[STEP_STRIDE];

    for (int t = 0; t < T_STEPS; ++t) {
        // Prefetch step t+2 before the fmac chain.
        float xn = 0.0f;
        if (t + 2 < T_STEPS) xn = xp[(size_t)(t + 2) * STEP_STRIDE];

        // Charge
        const float x = x0 + fb;   // x_t + feedback (matches ref op order)
        v = v + x;
        // Fire (heaviside on v - 1.0)
        const bool  sp = (v - 1.0f) >= 0.0f;
        const float sf = sp ? 1.0f : 0.0f;
        // Hard reset
        v = sp ? 0.0f : v;

        // Emit spike (non-temporal: don't let the 256MiB output stream
        // evict the input from L3).
        __builtin_nontemporal_store(sf, op + (size_t)t * STEP_STRIDE);

        // Broadcast spike vector through LDS (wave-private row).
        sp_row[lane] = sf;
        __builtin_amdgcn_wave_barrier();   // compiler-only ordering, no code

        // Feedback matvec: fb[o] = sum_{d=0..63} s[d] * w[o][d] + bias[o]
        // Strict left-to-right order, single accumulator (bit-identical to
        // the previous passing kernel; fmaf exact since s[d] in {0,1}).
        float acc = 0.0f;
#pragma unroll
        for (int j = 0; j < 16; ++j) {
            const float4 s4 = sp4[j];   // all lanes same addr -> LDS broadcast
            acc = fmaf(s4.x, w[4 * j + 0], acc);
            acc = fmaf(s4.y, w[4 * j + 1], acc);
            acc = fmaf(s4.z, w[4 * j + 2], acc);
            acc = fmaf(s4.w, w[4 * j + 3], acc);
        }
        fb = acc + bias;
        __builtin_amdgcn_wave_barrier();   // keep next step's ds_write behind reads

        x0 = x1;
        x1 = xn;
    }
}

extern "C" void kernel_launch(void* const* d_in, const int* in_sizes, int n_in,
                              void* d_out, int out_size, void* d_ws, size_t ws_size,
                              hipStream_t stream) {
    const float* x_seq  = (const float*)d_in[0];
    const float* conn_w = (const float*)d_in[1];
    const float* conn_b = (const float*)d_in[2];
    float* out = (float*)d_out;

    dim3 grid(8192);   // 32768 chains / 4 waves per block
    dim3 block(256);
    hipLaunchKernelGGL(ilc_snn_kernel, grid, block, 0, stream,
                       x_seq, conn_w, conn_b, out);
}

// Round 3
// 664.655 us; speedup vs baseline: 1.0040x; 1.0040x over previous
//
#include <hip/hip_runtime.h>

// ILCBaseNode: T=32 steps of IF-neuron + grouped-conv feedback.
// One wave (64 lanes) per (batch, group) chain; lane o = output neuron o.
// 32768 chains = 8192 blocks x 4 waves.
//
// R3: register-allocation root cause. R0's counters (VGPR=40, occ 60.8% ->
//     ~104 total regs) show the compiler honored the launch_bounds(256,4)
//     4-wave pressure target by parking w[64] in AGPRs (gfx908-era "AGPRs
//     are free spill space" heuristic; on gfx950's unified file this buys
//     nothing) and paying v_accvgpr_read per fmac (~2x VALU instrs/step).
//     Fix: amdgpu_waves_per_eu(1) raises the scheduler's pressure limit to
//     512 regs -> no AGPR spilling; w[64] stays in arch VGPRs. Natural
//     demand ~84 regs -> occupancy ~6 waves/EU (UP from 4.8).
//     Keep: readlane broadcast (R1 proved the LDS broadcast is LDS-pipe-
//     bound at ~338us), 2-deep x prefetch, non-temporal spike stores,
//     prologue asm pin (stops the loads sinking into the t-loop).

#define T_STEPS 32
#define BATCH 512
#define OUTD 4096           // 64 groups * 64 neurons
#define STEP_STRIDE ((size_t)BATCH * OUTD)

__global__ __launch_bounds__(256)
__attribute__((amdgpu_waves_per_eu(1)))
void ilc_snn_kernel(const float* __restrict__ x_seq,
                    const float* __restrict__ conn_w,
                    const float* __restrict__ conn_b,
                    float* __restrict__ out)
{
    const int lane  = threadIdx.x & 63;
    const int wid   = threadIdx.x >> 6;
    const int chain = blockIdx.x * 4 + wid;   // 0..32767
    const int b     = chain >> 6;             // 0..511
    const int a     = chain & 63;             // 0..63

    // Lane o holds weight row w[a][o][0..63] in 64 arch VGPRs.
    // asm pin: value origin becomes opaque -> loads can't be rematerialized
    // or sunk into the t-loop.
    float w[64];
    const float4* wq = (const float4*)(conn_w + ((size_t)(a * 64 + lane)) * 64);
#pragma unroll
    for (int k = 0; k < 16; ++k) {
        float4 q = wq[k];
        asm volatile("" : "+v"(q.x), "+v"(q.y), "+v"(q.z), "+v"(q.w));
        w[4 * k + 0] = q.x;
        w[4 * k + 1] = q.y;
        w[4 * k + 2] = q.z;
        w[4 * k + 3] = q.w;
    }
    const float bias = conn_b[a * 64 + lane];

    const size_t base = (size_t)b * OUTD + (size_t)(a * 64 + lane);
    const float* xp = x_seq + base;
    float* op = out + base;

    float v = 0.0f, fb = 0.0f;
    // 2-deep prefetch of the input stream.
    float x0 = xp[0];
    float x1 = xp[STEP_STRIDE];

    for (int t = 0; t < T_STEPS; ++t) {
        // Prefetch step t+2 before the fmac chain.
        float xn = 0.0f;
        if (t + 2 < T_STEPS) xn = xp[(size_t)(t + 2) * STEP_STRIDE];

        // Charge
        const float x = x0 + fb;   // x_t + feedback (matches ref op order)
        v = v + x;
        // Fire (heaviside on v - 1.0)
        const bool  sp = (v - 1.0f) >= 0.0f;
        const float sf = sp ? 1.0f : 0.0f;
        // Hard reset
        v = sp ? 0.0f : v;

        // Emit spike (non-temporal: keep the 256MiB output stream from
        // evicting the input from L3).
        __builtin_nontemporal_store(sf, op + (size_t)t * STEP_STRIDE);

        // Feedback matvec: fb[o] = sum_{d=0..63} s[d] * w[o][d] + bias[o]
        // Strict left-to-right order, single accumulator (bit-identical;
        // fmaf exact since s[d] in {0,1}).
        float acc = 0.0f;
        const int sfi = __builtin_bit_cast(int, sf);
#pragma unroll
        for (int d = 0; d < 64; ++d) {
            const int   sdi = __builtin_amdgcn_readlane(sfi, d);
            const float sd  = __builtin_bit_cast(float, sdi);
            acc = fmaf(sd, w[d], acc);
        }
        fb = acc + bias;

        x0 = x1;
        x1 = xn;
    }
}

extern "C" void kernel_launch(void* const* d_in, const int* in_sizes, int n_in,
                              void* d_out, int out_size, void* d_ws, size_t ws_size,
                              hipStream_t stream) {
    const float* x_seq  = (const float*)d_in[0];
    const float* conn_w = (const float*)d_in[1];
    const float* conn_b = (const float*)d_in[2];
    float* out = (float*)d_out;

    dim3 grid(8192);   // 32768 chains / 4 waves per block
    dim3 block(256);
    hipLaunchKernelGGL(ilc_snn_kernel, grid, block, 0, stream,
                       x_seq, conn_w, conn_b, out);
}

// Round 4
// 587.846 us; speedup vs baseline: 1.1352x; 1.1307x over previous
//
#include <hip/hip_runtime.h>

// ILCBaseNode: T=32 steps of IF-neuron + grouped-conv feedback.
// One wave (64 lanes) per (batch, group) chain; lane o = output neuron o.
// 32768 chains = 8192 blocks x 4 waves.
//
// R4: exact revert to the 281us R0 structure (launch_bounds(256,4), plain
//     stores, 1-deep prefetch) + ONE change: an empty asm with all 64 w[i]
//     as "+v" operands INSIDE the t-loop. Occupancy arithmetic proves the
//     AGPR parking: R0 had VGPR_Count=40 but occ 60.8% = 4.9 waves/SIMD =
//     512/104 total regs = 40 arch + 64 AGPR for w[]; each fmac then pays a
//     v_accvgpr_read (~128 extra cyc/step, matching the 430-cyc/step busy
//     budget). A "v"-class constraint re-asserted every iteration makes an
//     AGPR home cost 64 moves/iter, so regalloc must keep w[] in arch VGPRs
//     (40+64+misc ~ 110 fits the 128-reg budget at 4 waves/EU).
//     NOT viable (ruled out by arithmetic/measurement, do not revisit):
//     - LDS spike broadcast: LDS-pipe-bound at ~377us (R1 measured).
//     - Any accumulation reorder (MFMA, pairwise, pk_fma): ~1e-7 diffs x
//       6.7e7 threshold crossings -> ~10 cascading spike flips -> fails.
//     - ballot + SALU bit-expand: 128 SALU/step on the per-CU scalar unit
//       -> 2048 cyc/CU-round, worse than the 1720 VALU-bound present.

#define T_STEPS 32
#define BATCH 512
#define OUTD 4096           // 64 groups * 64 neurons
#define STEP_STRIDE ((size_t)BATCH * OUTD)

__global__ __launch_bounds__(256, 4)
void ilc_snn_kernel(const float* __restrict__ x_seq,
                    const float* __restrict__ conn_w,
                    const float* __restrict__ conn_b,
                    float* __restrict__ out)
{
    const int lane  = threadIdx.x & 63;
    const int wid   = threadIdx.x >> 6;
    const int chain = blockIdx.x * 4 + wid;   // 0..32767
    const int b     = chain >> 6;             // 0..511
    const int a     = chain & 63;             // 0..63

    // Lane o holds weight row w[a][o][0..63]; the in-loop pin below forces
    // these into arch VGPRs for the lifetime of the t-loop.
    float w[64];
    const float* wrow = conn_w + ((size_t)(a * 64 + lane)) * 64;
#pragma unroll
    for (int k = 0; k < 16; ++k) {
        const float4 q = *(const float4*)(wrow + 4 * k);
        w[4 * k + 0] = q.x;
        w[4 * k + 1] = q.y;
        w[4 * k + 2] = q.z;
        w[4 * k + 3] = q.w;
    }
    const float bias = conn_b[a * 64 + lane];

    const size_t base = (size_t)b * OUTD + (size_t)(a * 64 + lane);
    const float* xp = x_seq + base;
    float* op = out + base;

    float v = 0.0f, fb = 0.0f;
    float xt = xp[0];   // prefetch step 0

    for (int t = 0; t < T_STEPS; ++t) {
        // Arch-VGPR pin: a "v" register-class constraint on every w[i],
        // re-asserted each iteration. Emits no code; makes AGPR homing of
        // w[] cost 64 accvgpr moves per iteration, so regalloc keeps the
        // weights in arch VGPRs instead.
        asm volatile("" :
            "+v"(w[ 0]), "+v"(w[ 1]), "+v"(w[ 2]), "+v"(w[ 3]),
            "+v"(w[ 4]), "+v"(w[ 5]), "+v"(w[ 6]), "+v"(w[ 7]),
            "+v"(w[ 8]), "+v"(w[ 9]), "+v"(w[10]), "+v"(w[11]),
            "+v"(w[12]), "+v"(w[13]), "+v"(w[14]), "+v"(w[15]),
            "+v"(w[16]), "+v"(w[17]), "+v"(w[18]), "+v"(w[19]),
            "+v"(w[20]), "+v"(w[21]), "+v"(w[22]), "+v"(w[23]),
            "+v"(w[24]), "+v"(w[25]), "+v"(w[26]), "+v"(w[27]),
            "+v"(w[28]), "+v"(w[29]), "+v"(w[30]), "+v"(w[31]),
            "+v"(w[32]), "+v"(w[33]), "+v"(w[34]), "+v"(w[35]),
            "+v"(w[36]), "+v"(w[37]), "+v"(w[38]), "+v"(w[39]),
            "+v"(w[40]), "+v"(w[41]), "+v"(w[42]), "+v"(w[43]),
            "+v"(w[44]), "+v"(w[45]), "+v"(w[46]), "+v"(w[47]),
            "+v"(w[48]), "+v"(w[49]), "+v"(w[50]), "+v"(w[51]),
            "+v"(w[52]), "+v"(w[53]), "+v"(w[54]), "+v"(w[55]),
            "+v"(w[56]), "+v"(w[57]), "+v"(w[58]), "+v"(w[59]),
            "+v"(w[60]), "+v"(w[61]), "+v"(w[62]), "+v"(w[63]));

        // Prefetch next step's input before the long fmac chain.
        float xnext = 0.0f;
        if (t + 1 < T_STEPS) xnext = xp[(size_t)(t + 1) * STEP_STRIDE];

        // Charge
        const float x = xt + fb;   // x_t + feedback (matches ref op order)
        v = v + x;
        // Fire (heaviside on v - 1.0)
        const bool  sp = (v - 1.0f) >= 0.0f;
        const float sf = sp ? 1.0f : 0.0f;
        // Hard reset
        v = sp ? 0.0f : v;
        // Emit spike
        op[(size_t)t * STEP_STRIDE] = sf;

        // Feedback matvec: fb[o] = sum_{d=0..63} s[d] * w[o][d] + bias[o]
        // Strict left-to-right order, single accumulator (bit-identical to
        // the reference's sequential fp32 contraction; products exact since
        // s[d] in {0,1}).
        float acc = 0.0f;
        const int sfi = __builtin_bit_cast(int, sf);
#pragma unroll
        for (int d = 0; d < 64; ++d) {
            const int   sdi = __builtin_amdgcn_readlane(sfi, d);
            const float sd  = __builtin_bit_cast(float, sdi);
            acc = fmaf(sd, w[d], acc);
        }
        fb = acc + bias;

        xt = xnext;
    }
}

extern "C" void kernel_launch(void* const* d_in, const int* in_sizes, int n_in,
                              void* d_out, int out_size, void* d_ws, size_t ws_size,
                              hipStream_t stream) {
    const float* x_seq  = (const float*)d_in[0];
    const float* conn_w = (const float*)d_in[1];
    const float* conn_b = (const float*)d_in[2];
    float* out = (float*)d_out;

    dim3 grid(8192);   // 32768 chains / 4 waves per block
    dim3 block(256);
    hipLaunchKernelGGL(ilc_snn_kernel, grid, block, 0, stream,
                       x_seq, conn_w, conn_b, out);
}

// Round 7
// 574.770 us; speedup vs baseline: 1.1611x; 1.0227x over previous
//
#include <hip/hip_runtime.h>

// ILCBaseNode: T=32 steps of IF-neuron + grouped-conv feedback.
// One wave (64 lanes) per (batch, group) chain; lane o = output neuron o.
// 32768 chains = 8192 blocks x 4 waves.
//
// R7: asm matvec, hazard-corrected. R5/R6 failed IDENTICALLY (absmax 468)
//     -> allocation-independent bug: wait-state violations. v_readlane is
//     lane-crossing (non-interlocked like DPP): (1) its SGPR write needs
//     >=4 slots before a VALU constant-read -- my prologue had 3; (2) its
//     VGPR source must not be written by the immediately-preceding VALU --
//     block 1's first readlane could issue right after the v_cndmask
//     writing sfr. Compiler codegen handles both (R0/R4 pass); inside asm
//     they're on me. Fix: 5 rotating SGPR temps (all write->read
//     distances >=4, hand-verified) + s_nop 3 ahead of block 1.
//     Also: W operands are now "+v" IN-OUT, not inputs -- R5/R6 let the
//     compiler satisfy "v" inputs with 16 v_accvgpr_read copies per block
//     while keeping w[] AGPR-homed. In-out makes AGPR-home cost 128
//     copies/step, flipping regalloc to arch-home (64 W + ~30 live < 128
//     budget at 4 waves/EU).
//     Fork: (a) pass + VGPR>=100 + ~150us -> AGPR theory confirmed.
//     (b) pass + VGPR=40 + ~290us -> asm route exhausted, pivot structure.
//     (c) same 468 failure -> abandon asm permanently, revert to R4.
//     Ruled out (do not revisit): LDS spike broadcast (R1: 377us,
//     LDS-pipe-bound); any accumulation reorder incl. MFMA/split-acc
//     (bit-exactness: ~10 cascading spike flips expected); ballot+SALU
//     bit-expand (1 scalar unit/CU -> 2048 SALU cyc/CU/step, worse).

#define T_STEPS 32
#define BATCH 512
#define OUTD 4096           // 64 groups * 64 neurons
#define STEP_STRIDE ((size_t)BATCH * OUTD)

// One 16-wide matvec slice. Operands: %0-%4 = SGPR temps t0-t4, %5 = acc
// (early-clobber in-out), %6-%21 = W[0..15] (in-out "+v": forces arch-VGPR
// economics), %22 = sfr (spike VGPR). Schedule: 5-deep readlane prologue,
// then fmac/readlane interleave; every readlane SGPR write has >=4
// instruction slots before its consuming fmac. Accumulation strictly
// ascending d, single accumulator (bit-exact; s[d] in {0,1}).
#define MV16(pre,d0,d1,d2,d3,d4,d5,d6,d7,d8,d9,d10,d11,d12,d13,d14,d15, W) \
  asm(pre                                                                 \
      "v_readlane_b32 %0, %22, " #d0 "\n\t"                               \
      "v_readlane_b32 %1, %22, " #d1 "\n\t"                               \
      "v_readlane_b32 %2, %22, " #d2 "\n\t"                               \
      "v_readlane_b32 %3, %22, " #d3 "\n\t"                               \
      "v_readlane_b32 %4, %22, " #d4 "\n\t"                               \
      "v_fmac_f32 %5, %0, %6\n\t"                                         \
      "v_readlane_b32 %0, %22, " #d5 "\n\t"                               \
      "v_fmac_f32 %5, %1, %7\n\t"                                         \
      "v_readlane_b32 %1, %22, " #d6 "\n\t"                               \
      "v_fmac_f32 %5, %2, %8\n\t"                                         \
      "v_readlane_b32 %2, %22, " #d7 "\n\t"                               \
      "v_fmac_f32 %5, %3, %9\n\t"                                         \
      "v_readlane_b32 %3, %22, " #d8 "\n\t"                               \
      "v_fmac_f32 %5, %4, %10\n\t"                                        \
      "v_readlane_b32 %4, %22, " #d9 "\n\t"                               \
      "v_fmac_f32 %5, %0, %11\n\t"                                        \
      "v_readlane_b32 %0, %22, " #d10 "\n\t"                              \
      "v_fmac_f32 %5, %1, %12\n\t"                                        \
      "v_readlane_b32 %1, %22, " #d11 "\n\t"                              \
      "v_fmac_f32 %5, %2, %13\n\t"                                        \
      "v_readlane_b32 %2, %22, " #d12 "\n\t"                              \
      "v_fmac_f32 %5, %3, %14\n\t"                                        \
      "v_readlane_b32 %3, %22, " #d13 "\n\t"                              \
      "v_fmac_f32 %5, %4, %15\n\t"                                        \
      "v_readlane_b32 %4, %22, " #d14 "\n\t"                              \
      "v_fmac_f32 %5, %0, %16\n\t"                                        \
      "v_readlane_b32 %0, %22, " #d15 "\n\t"                              \
      "v_fmac_f32 %5, %1, %17\n\t"                                        \
      "v_fmac_f32 %5, %2, %18\n\t"                                        \
      "v_fmac_f32 %5, %3, %19\n\t"                                        \
      "v_fmac_f32 %5, %4, %20\n\t"                                        \
      "v_fmac_f32 %5, %0, %21\n\t"                                        \
      : "=&s"(t0), "=&s"(t1), "=&s"(t2), "=&s"(t3), "=&s"(t4),            \
        "+&v"(acc),                                                       \
        "+v"(W[0]),  "+v"(W[1]),  "+v"(W[2]),  "+v"(W[3]),                \
        "+v"(W[4]),  "+v"(W[5]),  "+v"(W[6]),  "+v"(W[7]),                \
        "+v"(W[8]),  "+v"(W[9]),  "+v"(W[10]), "+v"(W[11]),               \
        "+v"(W[12]), "+v"(W[13]), "+v"(W[14]), "+v"(W[15])                \
      : "v"(sfr))

__global__ __launch_bounds__(256, 4)
void ilc_snn_kernel(const float* __restrict__ x_seq,
                    const float* __restrict__ conn_w,
                    const float* __restrict__ conn_b,
                    float* __restrict__ out)
{
    const int lane  = threadIdx.x & 63;
    const int wid   = threadIdx.x >> 6;
    const int chain = blockIdx.x * 4 + wid;   // 0..32767
    const int b     = chain >> 6;             // 0..511
    const int a     = chain & 63;             // 0..63

    // Lane o holds weight row w[a][o][0..63].
    float w[64];
    const float* wrow = conn_w + ((size_t)(a * 64 + lane)) * 64;
#pragma unroll
    for (int k = 0; k < 16; ++k) {
        const float4 q = *(const float4*)(wrow + 4 * k);
        w[4 * k + 0] = q.x;
        w[4 * k + 1] = q.y;
        w[4 * k + 2] = q.z;
        w[4 * k + 3] = q.w;
    }
    const float bias = conn_b[a * 64 + lane];

    const size_t base = (size_t)b * OUTD + (size_t)(a * 64 + lane);
    const float* xp = x_seq + base;
    float* op = out + base;

    float v = 0.0f, fb = 0.0f;
    float xt = xp[0];   // prefetch step 0
    int t0, t1, t2, t3, t4; // rotating SGPR temps for the asm matvec

    for (int t = 0; t < T_STEPS; ++t) {
        // Prefetch next step's input before the long fmac chain.
        float xnext = 0.0f;
        if (t + 1 < T_STEPS) xnext = xp[(size_t)(t + 1) * STEP_STRIDE];

        // Charge
        const float x = xt + fb;   // x_t + feedback (matches ref op order)
        v = v + x;
        // Fire (heaviside on v - 1.0)
        const bool  sp = (v - 1.0f) >= 0.0f;
        const float sf = sp ? 1.0f : 0.0f;
        // Hard reset
        v = sp ? 0.0f : v;
        // Emit spike
        op[(size_t)t * STEP_STRIDE] = sf;

        // Feedback matvec: fb[o] = sum_{d=0..63} s[d] * w[o][d] + bias[o]
        float acc = 0.0f;
        const float sfr = sf;
        // Block 1 carries s_nop 3: sfr was just written by a VALU
        // (v_cndmask); readlane's lane-crossing source read is not
        // interlocked against it.
        MV16("s_nop 3\n\t",
              0, 1, 2, 3, 4, 5, 6, 7, 8, 9,10,11,12,13,14,15, (&w[0]));
        MV16("",
             16,17,18,19,20,21,22,23,24,25,26,27,28,29,30,31, (&w[16]));
        MV16("",
             32,33,34,35,36,37,38,39,40,41,42,43,44,45,46,47, (&w[32]));
        MV16("",
             48,49,50,51,52,53,54,55,56,57,58,59,60,61,62,63, (&w[48]));
        fb = acc + bias;

        xt = xnext;
    }
}

extern "C" void kernel_launch(void* const* d_in, const int* in_sizes, int n_in,
                              void* d_out, int out_size, void* d_ws, size_t ws_size,
                              hipStream_t stream) {
    const float* x_seq  = (const float*)d_in[0];
    const float* conn_w = (const float*)d_in[1];
    const float* conn_b = (const float*)d_in[2];
    float* out = (float*)d_out;

    dim3 grid(8192);   // 32768 chains / 4 waves per block
    dim3 block(256);
    hipLaunchKernelGGL(ilc_snn_kernel, grid, block, 0, stream,
                       x_seq, conn_w, conn_b, out);
}